// Round 6
// baseline (384.769 us; speedup 1.0000x reference)
//
#include <hip/hip_runtime.h>
#include <hip/hip_bf16.h>

typedef __hip_bfloat16 bf16;
typedef __attribute__((ext_vector_type(8))) short short8;
typedef __attribute__((ext_vector_type(8))) unsigned short ushort8;
typedef __attribute__((ext_vector_type(4))) float floatx4;

__device__ __forceinline__ short f2s(float x) {
  bf16 h = __float2bfloat16(x);
  short s;
  __builtin_memcpy(&s, &h, 2);
  return s;
}

__device__ __forceinline__ void gl_lds16(const bf16* g, bf16* l) {
  __builtin_amdgcn_global_load_lds(
      (const __attribute__((address_space(1))) unsigned int*)g,
      (__attribute__((address_space(3))) unsigned int*)l, 16, 0, 0);
}

#define MFMA16(a, b, c) __builtin_amdgcn_mfma_f32_16x16x32_bf16((a), (b), (c), 0, 0, 0)

// raw workgroup barrier with compiler memory fences (no vmcnt(0) drain)
__device__ __forceinline__ void bar() {
  asm volatile("" ::: "memory");
  __builtin_amdgcn_s_barrier();
  asm volatile("" ::: "memory");
}

#define VMCNT(N) asm volatile("s_waitcnt vmcnt(" #N ")" ::: "memory")

// fp32 -> bf16 elementwise convert; each thread handles 8 elements.
__global__ __launch_bounds__(256) void convert_f32_bf16(
    const float* __restrict__ src, bf16* __restrict__ dst, int n) {
  const int i = (blockIdx.x * 256 + threadIdx.x) * 8;
  if (i + 7 < n) {
    float4 a = *(const float4*)(src + i);
    float4 b = *(const float4*)(src + i + 4);
    short8 r;
    r[0] = f2s(a.x); r[1] = f2s(a.y); r[2] = f2s(a.z); r[3] = f2s(a.w);
    r[4] = f2s(b.x); r[5] = f2s(b.y); r[6] = f2s(b.z); r[7] = f2s(b.w);
    *(short8*)(dst + i) = r;
  }
}

// One-block precompute: bf16 e-tables (zero-padded to 16 rows each) + exact-fp32 S4.
__global__ __launch_bounds__(256) void precompute_tables(
    const float* __restrict__ eqh, const float* __restrict__ eqw,
    const float* __restrict__ ekh, const float* __restrict__ ekw,
    const float* __restrict__ evh, const float* __restrict__ evw,
    bf16* __restrict__ ews, float* __restrict__ S4f)
{
  const int t = threadIdx.x;
  if (t < 96) {
    const int tb = t >> 4, row = t & 15;
    const float* src[6] = {eqh, eqw, ekh, ekw, evh, evw};
    bf16* dst = ews + tb * 1024 + row * 64;
    if (row < 15) {
      const float* s = src[tb] + row * 64;
      #pragma unroll
      for (int d = 0; d < 64; d += 8) {
        float4 a = *(const float4*)(s + d);
        float4 b2 = *(const float4*)(s + d + 4);
        short8 rr;
        rr[0] = f2s(a.x); rr[1] = f2s(a.y); rr[2] = f2s(a.z); rr[3] = f2s(a.w);
        rr[4] = f2s(b2.x); rr[5] = f2s(b2.y); rr[6] = f2s(b2.z); rr[7] = f2s(b2.w);
        *(short8*)(dst + d) = rr;
      }
    } else {
      const short8 z = {0, 0, 0, 0, 0, 0, 0, 0};
      #pragma unroll
      for (int d = 0; d < 64; d += 8) *(short8*)(dst + d) = z;
    }
  }
  if (t < 225) {
    const int r = t / 15, c = t % 15;
    float s = 0.f;
    for (int d = 0; d < 64; ++d)
      s += (eqh[r * 64 + d] + eqw[c * 64 + d]) * (ekh[r * 64 + d] + ekw[c * 64 + d]);
    S4f[t] = s;
  }
}

// ---------------------------------------------------------------------------
// 256x256-tile GEMM, C = A @ W^T (+bias), bf16 inputs.
// 8 waves (2M x 4N), 128x64 per wave. BK=32, 4-deep LDS ring (4 x 32KB),
// prefetch depth 3 K-tiles, counted vmcnt(8) once per K-tile (T3+T4),
// st_16x32 subtiled XOR LDS layout staged via pre-swizzled global source
// (T2, rule #21), setprio around MFMA clusters (T5).
//
// r6: ONE barrier per tile (the deep-prefetch + minimal-barrier quadrant).
// A/B history: r3 {3-tile lead, 4 bars/K64} = 134us; r4 {3-tile, 8 bars} =
// 147us; r5 {1-tile lead, 2 bars} = 170us -> prefetch lead dominates, bars
// cost ~3us/8. This round: {3-tile lead, 2 bars/K64}.
// Soundness of single {vmcnt(8); bar} per tile:
//   - reads of slot t: prior tile's vmcnt(8) retired each wave's slot-t
//     loads BEFORE the barrier; barrier joins all waves. cross-wave safe.
//   - staging into slot (t+3)&3 == (t-1)&3: all waves finished reading
//     slot t-1 before the same barrier. no intra-tile hazard remains.
//
// T1: XCD k owns bx in [k*nx/8,(k+1)*nx/8) for ALL by panels (FETCH
// 203->74MB, r2->r3). Epilogue: direct scatter stores (r2's LDS-transpose
// epilogue spilled acc to scratch: VGPR 92 < 128 needed, +437MB write).
//
// Per-thread vmcnt ledger (4 loads per K-tile: Aq0,Aq1,Bq0,Bq1):
//   steady in-flight at tile end: t+1(4), t+2(4), t+3(4) = 12;
//   VMCNT(8) retires tile t+1. Tail: vmcnt(4), vmcnt(0).
// ---------------------------------------------------------------------------
template <int TAG>
__global__ __launch_bounds__(512, 2) void gemm256(
    const bf16* __restrict__ A,
    const bf16* __restrict__ W0, const bf16* __restrict__ W1, const bf16* __restrict__ W2,
    const float* __restrict__ bias, int hasBias,
    bf16* __restrict__ O0, bf16* __restrict__ O1, bf16* __restrict__ O2,
    float* __restrict__ Ofp, int outF32)
{
  __shared__ bf16 lds[65536];   // 128 KB: 4 bufs x (A 8192 + B 8192 elems)

  // XCD-aware mapping: xcd = dispatch_id % 8 (HW round-robin); each XCD gets
  // a contiguous bx chunk across all by panels, bx-minor within the XCD.
  const int nx = gridDim.x;
  const int orig = blockIdx.y * nx + blockIdx.x;
  const int xcd = orig & 7;
  const int c = orig >> 3;
  const int bxp = nx >> 3;               // bx per XCD (nx % 8 == 0 in all paths)
  const int bx = xcd * bxp + (c % bxp);
  const int by = c / bxp;

  const int m0 = bx * 256;
  const int which = by >> 2;
  const bf16* W = (which == 0) ? W0 : (which == 1) ? W1 : W2;
  bf16* O = (which == 0) ? O0 : (which == 1) ? O1 : O2;
  const int n0 = (by & 3) * 256;

  const int t = threadIdx.x;
  const int lane = t & 63, w = t >> 6;
  const int wm = w >> 2, wn = w & 3;
  const int quad = lane >> 4, n16 = lane & 15;

  // staging source coordinates (inverse of the LDS st_16x32 swizzle)
  const int srow = (t >> 6) * 16 + ((t & 63) >> 2);
  const int scol = ((t & 3) * 8) ^ (((t >> 5) & 1) << 4);
  const bf16* Abase = A + (m0 + srow) * 1024 + scol;
  const bf16* Bbase = W + (n0 + srow) * 1024 + scol;
  const int wdst = w * 512;               // wave-uniform LDS dest (HW adds lane*16B)

  // fragment read offsets (swizzled)
  const int swzq = (quad * 8) ^ ((n16 >> 3) << 4);
  const int aoff = wm * 4096 + n16 * 32 + swzq;   // + mi*512 (+2048 for mi 4..7)
  const int boff = wn * 2048 + n16 * 32 + swzq;   // + ni*512

  floatx4 acc[8][4];
  const floatx4 zero4 = {0.f, 0.f, 0.f, 0.f};
  #pragma unroll
  for (int mi = 0; mi < 8; ++mi)
    #pragma unroll
    for (int ni = 0; ni < 4; ++ni) acc[mi][ni] = zero4;

  // prologue: stage tiles 0,1,2 into ring slots 0,1,2
  #pragma unroll
  for (int p = 0; p < 3; ++p) {
    const bf16* ga = Abase + p * 32;
    bf16* la = lds + p * 16384 + wdst;
    gl_lds16(ga, la); gl_lds16(ga + 131072, la + 4096);
    const bf16* gb = Bbase + p * 32;
    bf16* lb = lds + p * 16384 + 8192 + wdst;
    gl_lds16(gb, lb); gl_lds16(gb + 131072, lb + 4096);
  }
  VMCNT(8);      // tile 0 landed; tiles 1,2 (8 loads) stay in flight
  bar();

#define TILE_STEP(TT, DOSTAGE, WAITSEQ) do {                                   \
    const bf16* bA_ = lds + ((TT) & 3) * 16384;                                \
    const bf16* bB_ = bA_ + 8192;                                              \
    short8 af_[4], bq_[4];                                                     \
    _Pragma("unroll")                                                          \
    for (int mi = 0; mi < 4; ++mi)                                             \
      af_[mi] = *(const short8*)(bA_ + aoff + mi * 512);                       \
    _Pragma("unroll")                                                          \
    for (int ni = 0; ni < 4; ++ni)                                             \
      bq_[ni] = *(const short8*)(bB_ + boff + ni * 512);                       \
    if (DOSTAGE) {                                                             \
      const bf16* g_ = Abase + ((TT) + 3) * 32;                                \
      bf16* l_ = lds + (((TT) + 3) & 3) * 16384 + wdst;                        \
      gl_lds16(g_, l_); gl_lds16(g_ + 131072, l_ + 4096);                      \
    }                                                                          \
    __builtin_amdgcn_s_setprio(1);                                             \
    _Pragma("unroll")                                                          \
    for (int mi = 0; mi < 4; ++mi)                                             \
      _Pragma("unroll")                                                        \
      for (int ni = 0; ni < 4; ++ni)                                           \
        acc[mi][ni] = MFMA16(af_[mi], bq_[ni], acc[mi][ni]);                   \
    __builtin_amdgcn_s_setprio(0);                                             \
    _Pragma("unroll")                                                          \
    for (int mi = 0; mi < 4; ++mi)                                             \
      af_[mi] = *(const short8*)(bA_ + aoff + 2048 + mi * 512);                \
    if (DOSTAGE) {                                                             \
      const bf16* g_ = Bbase + ((TT) + 3) * 32;                                \
      bf16* l_ = lds + (((TT) + 3) & 3) * 16384 + 8192 + wdst;                 \
      gl_lds16(g_, l_); gl_lds16(g_ + 131072, l_ + 4096);                      \
    }                                                                          \
    __builtin_amdgcn_s_setprio(1);                                             \
    _Pragma("unroll")                                                          \
    for (int mi = 0; mi < 4; ++mi)                                             \
      _Pragma("unroll")                                                        \
      for (int ni = 0; ni < 4; ++ni)                                           \
        acc[mi + 4][ni] = MFMA16(af_[mi], bq_[ni], acc[mi + 4][ni]);           \
    __builtin_amdgcn_s_setprio(0);                                             \
    WAITSEQ;                                                                   \
  } while (0)

  #pragma unroll 1
  for (int tt = 0; tt < 29; ++tt) {
    TILE_STEP(tt, 1, VMCNT(8); bar());
  }
  TILE_STEP(29, 0, VMCNT(4); bar());
  TILE_STEP(30, 0, VMCNT(0); bar());
  TILE_STEP(31, 0, (void)0);
#undef TILE_STEP

  // ---- epilogue: direct scatter stores (LDS-transpose variant spills acc
  // to scratch at this register pressure — measured r2) ----
  #pragma unroll
  for (int ni = 0; ni < 4; ++ni) {
    const int col = n0 + wn * 64 + ni * 16 + n16;
    const float bv = hasBias ? bias[col] : 0.f;
    #pragma unroll
    for (int mi = 0; mi < 8; ++mi) {
      #pragma unroll
      for (int r = 0; r < 4; ++r) {
        const int row = m0 + wm * 128 + mi * 16 + quad * 4 + r;
        if (outF32) Ofp[row * 1024 + col] = acc[mi][ni][r] + bv;
        else        O[row * 1024 + col] = __float2bfloat16(acc[mi][ni][r] + bv);
      }
    }
  }
}

// Legacy 128^2-tile GEMM — kept only for the fp32-weight fallback path.
template <int TAG>
__global__ __launch_bounds__(256) void gemm_bt(
    const bf16* __restrict__ A,
    const void* __restrict__ W0, const void* __restrict__ W1, const void* __restrict__ W2,
    int wBf,
    const float* __restrict__ bias, int hasBias,
    bf16* __restrict__ O0, bf16* __restrict__ O1, bf16* __restrict__ O2,
    float* __restrict__ Ofp, int outF32)
{
  __shared__ bf16 As[128 * 64];
  __shared__ bf16 Bs[128 * 64];

  const int m0 = blockIdx.x * 128;
  const int by = blockIdx.y;
  const int which = by >> 3;
  const void* W = (which == 0) ? W0 : (which == 1) ? W1 : W2;
  bf16* O = (which == 0) ? O0 : (which == 1) ? O1 : O2;
  const int n0 = (by & 7) * 128;

  const int t = threadIdx.x;
  const int lane = t & 63, w = t >> 6;
  const int lrow = lane >> 3, lcol = (lane & 7) * 8;
  const int wm = w >> 1, wn = w & 1;
  const int quad = lane >> 4, n16 = lane & 15;

  const int swzA = ((lrow & 1) << 5) | (((lrow >> 1) & 3) << 3);
  const int gcol = lcol ^ swzA;
  const int swzR = ((n16 & 1) << 5) | (((n16 >> 1) & 3) << 3);

  floatx4 acc[4][4];
  const floatx4 zero4 = {0.f, 0.f, 0.f, 0.f};
  #pragma unroll
  for (int mi = 0; mi < 4; ++mi)
    #pragma unroll
    for (int ni = 0; ni < 4; ++ni) acc[mi][ni] = zero4;

  const int arowb = m0 + w * 32 + lrow;
  const int browb = n0 + w * 32 + lrow;
  bf16* lau = As + w * 2048;
  bf16* lbu = Bs + w * 2048;

  if (wBf) {
    const bf16* Wb = (const bf16*)W;
    for (int k0 = 0; k0 < 1024; k0 += 64) {
      if (k0) __syncthreads();
      const bf16* ga = A + arowb * 1024 + k0 + gcol;
      const bf16* gw = Wb + browb * 1024 + k0 + gcol;
      #pragma unroll
      for (int c = 0; c < 4; ++c) {
        gl_lds16(ga + c * 8192, lau + c * 512);
        gl_lds16(gw + c * 8192, lbu + c * 512);
      }
      __syncthreads();
      #pragma unroll
      for (int ks = 0; ks < 2; ++ks) {
        short8 af[4], bfv[4];
        #pragma unroll
        for (int mi = 0; mi < 4; ++mi)
          af[mi] = *(const short8*)(As + (wm * 64 + mi * 16 + n16) * 64 +
                                    ((ks * 32 + quad * 8) ^ swzR));
        #pragma unroll
        for (int ni = 0; ni < 4; ++ni)
          bfv[ni] = *(const short8*)(Bs + (wn * 64 + ni * 16 + n16) * 64 +
                                     ((ks * 32 + quad * 8) ^ swzR));
        #pragma unroll
        for (int mi = 0; mi < 4; ++mi)
          #pragma unroll
          for (int ni = 0; ni < 4; ++ni)
            acc[mi][ni] = MFMA16(af[mi], bfv[ni], acc[mi][ni]);
      }
    }
  } else {
    const float* Wf = (const float*)W;
    for (int k0 = 0; k0 < 1024; k0 += 64) {
      short8 rb[4];
      #pragma unroll
      for (int c = 0; c < 4; ++c) {
        const float* f = Wf + (browb + c * 8) * 1024 + k0 + gcol;
        float4 a = *(const float4*)f;
        float4 b = *(const float4*)(f + 4);
        short8 r;
        r[0] = f2s(a.x); r[1] = f2s(a.y); r[2] = f2s(a.z); r[3] = f2s(a.w);
        r[4] = f2s(b.x); r[5] = f2s(b.y); r[6] = f2s(b.z); r[7] = f2s(b.w);
        rb[c] = r;
      }
      if (k0) __syncthreads();
      const bf16* ga = A + arowb * 1024 + k0 + gcol;
      #pragma unroll
      for (int c = 0; c < 4; ++c) {
        gl_lds16(ga + c * 8192, lau + c * 512);
        *(short8*)(lbu + lane * 8 + c * 512) = rb[c];
      }
      __syncthreads();
      #pragma unroll
      for (int ks = 0; ks < 2; ++ks) {
        short8 af[4], bfv[4];
        #pragma unroll
        for (int mi = 0; mi < 4; ++mi)
          af[mi] = *(const short8*)(As + (wm * 64 + mi * 16 + n16) * 64 +
                                    ((ks * 32 + quad * 8) ^ swzR));
        #pragma unroll
        for (int ni = 0; ni < 4; ++ni)
          bfv[ni] = *(const short8*)(Bs + (wn * 64 + ni * 16 + n16) * 64 +
                                     ((ks * 32 + quad * 8) ^ swzR));
        #pragma unroll
        for (int mi = 0; mi < 4; ++mi)
          #pragma unroll
          for (int ni = 0; ni < 4; ++ni)
            acc[mi][ni] = MFMA16(af[mi], bfv[ni], acc[mi][ni]);
      }
    }
  }

  #pragma unroll
  for (int ni = 0; ni < 4; ++ni) {
    const int col = n0 + wn * 64 + ni * 16 + n16;
    const float bv = hasBias ? bias[col] : 0.f;
    #pragma unroll
    for (int mi = 0; mi < 4; ++mi) {
      #pragma unroll
      for (int r = 0; r < 4; ++r) {
        const int row = m0 + wm * 64 + mi * 16 + quad * 4 + r;
        if (outF32) Ofp[row * 1024 + col] = acc[mi][ni][r] + bv;
        else        O[row * 1024 + col] = __float2bfloat16(acc[mi][ni][r] + bv);
      }
    }
  }
}

// One block per (b_local, h). Rel tables via MFMA; binning in registers.
__global__ __launch_bounds__(256, 3) void attn_rel(
    const bf16* __restrict__ Q, const bf16* __restrict__ Km, const bf16* __restrict__ V,
    const bf16* __restrict__ ews, const float* __restrict__ S4f,
    bf16* __restrict__ Ctx)
{
  __shared__ bf16 vT[64][106];      // [d][k]: k<64 v[j=k][d]; 64..78 ev_h; 79..93 ev_w; 94,95 zero
  __shared__ bf16 pa[64][104];      // [i][k]: k<64 attn; 64..78 P_h; 79..93 P_w; 94,95 zero
  __shared__ float Ahs[64][16], Aws[64][16];   // q_i . ek_h[r] / ek_w[c]  (col 15 = 0)
  __shared__ float Bhs[15][64], Bws[15][64];   // eq_h[r] . k_j / eq_w[c] . k_j
  __shared__ float S4s[225];

  const int t = threadIdx.x;
  const int b = blockIdx.x >> 4, h = blockIdx.x & 15;
  const int base = b * 65536 + h * 64;
  const int lane = t & 63, w = t >> 6;
  const int quad = lane >> 4, n16 = lane & 15;

  // ---- phase 0: fragment loads straight from global ----
  const bf16* qrow = Q + base + (w * 16 + n16) * 1024 + quad * 8;
  short8 aq0 = *(const short8*)(qrow);
  short8 aq1 = *(const short8*)(qrow + 32);
  short8 bk0[4], bk1[4];
  #pragma unroll
  for (int nj = 0; nj < 4; ++nj) {
    const bf16* krow = Km + base + (nj * 16 + n16) * 1024 + quad * 8;
    bk0[nj] = *(const short8*)(krow);
    bk1[nj] = *(const short8*)(krow + 32);
  }
  short8 ebf[4][2];   // B-frags of eqh,eqw,ekh,ekw (row 15 zeroed by precompute)
  #pragma unroll
  for (int tb = 0; tb < 4; ++tb) {
    const bf16* er = ews + tb * 1024 + n16 * 64 + quad * 8;
    ebf[tb][0] = *(const short8*)(er);
    ebf[tb][1] = *(const short8*)(er + 32);
  }

  // ---- phase 1: stage transposed V + ev augmentation + S4; zero pads ----
  {
    const int r = t >> 2, c0 = (t & 3) * 16;
    const bf16* vrow = V + base + r * 1024 + c0;
    int4 v0 = *(const int4*)(vrow);
    int4 v1 = *(const int4*)(vrow + 8);
    const unsigned short* p0 = (const unsigned short*)&v0;
    const unsigned short* p1 = (const unsigned short*)&v1;
    #pragma unroll
    for (int ii = 0; ii < 8; ++ii) {
      *(unsigned short*)&vT[c0 + ii][r] = p0[ii];
      *(unsigned short*)&vT[c0 + 8 + ii][r] = p1[ii];
    }
    if (t < 60) {
      const int r2 = t >> 2, d0 = (t & 3) * 16;
      ushort8 pe0 = *(const ushort8*)(ews + 4096 + r2 * 64 + d0);
      ushort8 pe1 = *(const ushort8*)(ews + 4096 + r2 * 64 + d0 + 8);
      ushort8 pf0 = *(const ushort8*)(ews + 5120 + r2 * 64 + d0);
      ushort8 pf1 = *(const ushort8*)(ews + 5120 + r2 * 64 + d0 + 8);
      #pragma unroll
      for (int ii = 0; ii < 8; ++ii) {
        *(unsigned short*)&vT[d0 + ii][64 + r2] = pe0[ii];
        *(unsigned short*)&vT[d0 + 8 + ii][64 + r2] = pe1[ii];
        *(unsigned short*)&vT[d0 + ii][79 + r2] = pf0[ii];
        *(unsigned short*)&vT[d0 + 8 + ii][79 + r2] = pf1[ii];
      }
    }
    if (t < 64) {
      *(unsigned short*)&vT[t][94] = 0; *(unsigned short*)&vT[t][95] = 0;
      *(unsigned short*)&pa[t][94] = 0; *(unsigned short*)&pa[t][95] = 0;
    }
    if (t < 225) S4s[t] = S4f[t];
  }

  // ---- phase A: MFMAs — QK^T + rel tables; write tables to LDS ----
  floatx4 cqk[4];
  #pragma unroll
  for (int nj = 0; nj < 4; ++nj) {
    floatx4 c = {0.f, 0.f, 0.f, 0.f};
    c = MFMA16(aq0, bk0[nj], c);
    c = MFMA16(aq1, bk1[nj], c);
    cqk[nj] = c;
  }
  {
    floatx4 cah = {0.f, 0.f, 0.f, 0.f}, caw = cah, cbh = cah, cbw = cah;
    cah = MFMA16(aq0, ebf[2][0], cah); cah = MFMA16(aq1, ebf[2][1], cah);
    caw = MFMA16(aq0, ebf[3][0], caw); caw = MFMA16(aq1, ebf[3][1], caw);
    cbh = MFMA16(bk0[w], ebf[0][0], cbh); cbh = MFMA16(bk1[w], ebf[0][1], cbh);
    cbw = MFMA16(bk0[w], ebf[1][0], cbw); cbw = MFMA16(bk1[w], ebf[1][1], cbw);
    #pragma unroll
    for (int r = 0; r < 4; ++r) {
      const int i = w * 16 + quad * 4 + r;   // row i for Ah/Aw; key index j for Bh/Bw
      Ahs[i][n16] = cah[r];
      Aws[i][n16] = caw[r];
      if (n16 < 15) { Bhs[n16][i] = cbh[r]; Bws[n16][i] = cbw[r]; }
    }
  }
  __syncthreads();

  // ---- phase 3: rel add + softmax + register binning; write pa (wave-own rows) ----
  const int i_base = w * 16 + quad * 4;
  float xv[4][4];
  #pragma unroll
  for (int nj = 0; nj < 4; ++nj) {
    const int j = nj * 16 + n16;
    const int rowj = j >> 3, colj = j & 7;
    #pragma unroll
    for (int r = 0; r < 4; ++r) {
      const int i = i_base + r;
      const int rowi = i >> 3, coli = i & 7;
      const int rr = rowi - rowj + 7, rc = coli - colj + 7;
      xv[r][nj] = (cqk[nj][r] + Ahs[i][rr] + Aws[i][rc] + Bhs[rr][j] + Bws[rc][j]
                   + S4s[rr * 15 + rc]) * 0.125f;
    }
  }
  #pragma unroll
  for (int r = 0; r < 4; ++r) {
    const int i = i_base + r;
    const int rowi = i >> 3, coli = i & 7;
    float mx = fmaxf(fmaxf(xv[r][0], xv[r][1]), fmaxf(xv[r][2], xv[r][3]));
    #pragma unroll
    for (int off = 1; off < 16; off <<= 1) mx = fmaxf(mx, __shfl_xor(mx, off));
    float p[4];
    float sm = 0.f;
    #pragma unroll
    for (int nj = 0; nj < 4; ++nj) { p[nj] = __expf(xv[r][nj] - mx); sm += p[nj]; }
    #pragma unroll
    for (int off = 1; off < 16; off <<= 1) sm += __shfl_xor(sm, off);
    const float inv = 1.0f / sm;
    #pragma unroll
    for (int nj = 0; nj < 4; ++nj) {
      p[nj] *= inv;
      pa[i][nj * 16 + n16] = __float2bfloat16(p[nj]);
    }
    // P_h: butterfly over the 8 lanes sharing n16>>3 -> Ph'[i][g = nj*2 + (n16>>3)]
    float ph[4];
    #pragma unroll
    for (int nj = 0; nj < 4; ++nj) {
      float v = p[nj];
      v += __shfl_xor(v, 1); v += __shfl_xor(v, 2); v += __shfl_xor(v, 4);
      ph[nj] = v;
    }
    // P_w: Pw'[i][c = n16&7]
    float s4 = p[0] + p[1] + p[2] + p[3];
    float pw = s4 + __shfl_xor(s4, 8);
    if ((n16 & 7) == 0) {
      const int hh = n16 >> 3;
      #pragma unroll
      for (int nj = 0; nj < 4; ++nj) {
        const int g = nj * 2 + hh;
        pa[i][64 + rowi + 7 - g] = __float2bfloat16(ph[nj]);
      }
    } else if (n16 < 8) {
      const int z = n16 - 1;
      pa[i][64 + (z < rowi ? z : z + 8)] = __float2bfloat16(0.f);
    }
    if (n16 < 8) {
      pa[i][79 + coli + 7 - n16] = __float2bfloat16(pw);
    } else {
      const int z = n16 - 8;
      pa[i][79 + (z < coli ? z : z + 8)] = __float2bfloat16(0.f);  // z=7 hits zero-pad col 94
    }
  }
  __threadfence_block();   // pa writes -> same-wave pa reads below

  // ---- phase 5: ctx = attn_aug (64x96) @ Vaug (96x64) ----
  short8 ap[3];
  #pragma unroll
  for (int ksb = 0; ksb < 3; ++ksb)
    ap[ksb] = *(const short8*)&pa[w * 16 + n16][ksb * 32 + quad * 8];
  #pragma unroll
  for (int nj = 0; nj < 4; ++nj) {
    floatx4 c = {0.f, 0.f, 0.f, 0.f};
    #pragma unroll
    for (int ksb = 0; ksb < 3; ++ksb) {
      short8 bv = *(const short8*)&vT[nj * 16 + n16][ksb * 32 + quad * 8];
      c = MFMA16(ap[ksb], bv, c);
    }
    #pragma unroll
    for (int r = 0; r < 4; ++r) {
      const int i = i_base + r;
      Ctx[base + i * 1024 + nj * 16 + n16] = __float2bfloat16(c[r]);
    }
  }
}

extern "C" void kernel_launch(void* const* d_in, const int* in_sizes, int n_in,
                              void* d_out, int out_size, void* d_ws, size_t ws_size,
                              hipStream_t stream) {
  const float* x   = (const float*)d_in[0];
  const float* wq  = (const float*)d_in[1];
  const float* wk  = (const float*)d_in[2];
  const float* wv  = (const float*)d_in[3];
  const float* wo  = (const float*)d_in[4];
  const float* bo  = (const float*)d_in[5];
  const float* eqh = (const float*)d_in[6];
  const float* eqw = (const float*)d_in[7];
  const float* ekh = (const float*)d_in[8];
  const float* ekw = (const float*)d_in[9];
  const float* evh = (const float*)d_in[10];
  const float* evw = (const float*)d_in[11];
  float* outf = (float*)d_out;

  // 16KB table header at the tail of ws (clear of qb/kb/weights in all modes).
  const size_t hdr = (ws_size - 16384) & ~(size_t)1023;
  bf16* ewsB = (bf16*)((char*)d_ws + hdr);
  float* S4f = (float*)((char*)d_ws + hdr + 12288);
  precompute_tables<<<1, 256, 0, stream>>>(eqh, eqw, ekh, ekw, evh, evw, ewsB, S4f);

  if (ws_size >= (size_t)73 * 1024 * 1024) {
    // -------- full-batch path: ws = q(32M) | k(32M) | weights(8M) --------
    bf16* qb = (bf16*)d_ws;
    bf16* kb = qb + 16777216;
    bf16* wqb = kb + 16777216;
    bf16* wkb = wqb + 1048576;
    bf16* wvb = wkb + 1048576;
    bf16* wob = wvb + 1048576;
    bf16* xb = (bf16*)d_out;                      // d_out[0,32M): x bf16 (dead after QKV gemm)
    bf16* vb = (bf16*)((char*)d_out + 33554432);  // d_out[32M,64M): v (dead after attn)

    convert_f32_bf16<<<8192, 256, 0, stream>>>(x, xb, 16777216);
    convert_f32_bf16<<<512, 256, 0, stream>>>(wq, wqb, 1048576);
    convert_f32_bf16<<<512, 256, 0, stream>>>(wk, wkb, 1048576);
    convert_f32_bf16<<<512, 256, 0, stream>>>(wv, wvb, 1048576);
    convert_f32_bf16<<<512, 256, 0, stream>>>(wo, wob, 1048576);

    gemm256<0><<<dim3(64, 12), 512, 0, stream>>>(
        xb, wqb, wkb, wvb, nullptr, 0, qb, kb, vb, nullptr, 0);
    attn_rel<<<dim3(4096), 256, 0, stream>>>(qb, kb, vb, ewsB, S4f, qb);
    gemm256<1><<<dim3(64, 4), 512, 0, stream>>>(
        qb, wob, nullptr, nullptr, bo, 1, nullptr, nullptr, nullptr, outf, 1);
  } else {
    // -------- halved path --------
    bf16* xb0 = (bf16*)((char*)d_out + 16777216);   // Q1
    bf16* xb1 = (bf16*)((char*)d_out + 50331648);   // Q3
    bf16* vQ2 = (bf16*)((char*)d_out + 33554432);   // Q2
    bf16* qb = (bf16*)d_ws;
    bf16* kb = qb + 8388608;
    const int fastW = (ws_size >= (size_t)42 * 1024 * 1024) ? 1 : 0;
    bf16* wqb = kb + 8388608;
    bf16* wkb = wqb + 1048576;
    bf16* wvb = wkb + 1048576;
    bf16* wob = wvb + 1048576;

    convert_f32_bf16<<<4096, 256, 0, stream>>>(x, xb0, 8388608);
    convert_f32_bf16<<<4096, 256, 0, stream>>>(x + 8388608, xb1, 8388608);
    if (fastW) {
      convert_f32_bf16<<<512, 256, 0, stream>>>(wq, wqb, 1048576);
      convert_f32_bf16<<<512, 256, 0, stream>>>(wk, wkb, 1048576);
      convert_f32_bf16<<<512, 256, 0, stream>>>(wv, wvb, 1048576);
      convert_f32_bf16<<<512, 256, 0, stream>>>(wo, wob, 1048576);
    }

    for (int hh = 0; hh < 2; ++hh) {
      const bf16* xh = hh ? xb1 : xb0;
      if (fastW) {
        gemm256<0><<<dim3(32, 12), 512, 0, stream>>>(
            xh, wqb, wkb, wvb, nullptr, 0, qb, kb, vQ2, nullptr, 0);
      } else {
        gemm_bt<0><<<dim3(64, 24), 256, 0, stream>>>(
            xh, (const void*)wq, (const void*)wk, (const void*)wv,
            0, nullptr, 0, qb, kb, vQ2, nullptr, 0);
      }
      attn_rel<<<dim3(2048), 256, 0, stream>>>(qb, kb, vQ2, ewsB, S4f, qb);
      if (fastW) {
        gemm256<1><<<dim3(32, 4), 512, 0, stream>>>(
            qb, wob, nullptr, nullptr, bo, 1, nullptr, nullptr, nullptr,
            outf + (size_t)hh * 8388608, 1);
      } else {
        gemm_bt<1><<<dim3(64, 8), 256, 0, stream>>>(
            qb, (const void*)wo, nullptr, nullptr,
            0, bo, 1, nullptr, nullptr, nullptr,
            outf + (size_t)hh * 8388608, 1);
      }
    }
  }
}

// Round 7
// 350.393 us; speedup vs baseline: 1.0981x; 1.0981x over previous
//
#include <hip/hip_runtime.h>
#include <hip/hip_bf16.h>

typedef __hip_bfloat16 bf16;
typedef __attribute__((ext_vector_type(8))) short short8;
typedef __attribute__((ext_vector_type(8))) unsigned short ushort8;
typedef __attribute__((ext_vector_type(4))) float floatx4;

__device__ __forceinline__ short f2s(float x) {
  bf16 h = __float2bfloat16(x);
  short s;
  __builtin_memcpy(&s, &h, 2);
  return s;
}

__device__ __forceinline__ void gl_lds16(const bf16* g, bf16* l) {
  __builtin_amdgcn_global_load_lds(
      (const __attribute__((address_space(1))) unsigned int*)g,
      (__attribute__((address_space(3))) unsigned int*)l, 16, 0, 0);
}

#define MFMA16(a, b, c) __builtin_amdgcn_mfma_f32_16x16x32_bf16((a), (b), (c), 0, 0, 0)

// raw workgroup barrier with compiler memory fences (no vmcnt(0) drain)
__device__ __forceinline__ void bar() {
  asm volatile("" ::: "memory");
  __builtin_amdgcn_s_barrier();
  asm volatile("" ::: "memory");
}

#define VMCNT(N) asm volatile("s_waitcnt vmcnt(" #N ")" ::: "memory")

__device__ __forceinline__ void cvt8(const float* s, bf16* dst) {
  float4 a = *(const float4*)s;
  float4 b = *(const float4*)(s + 4);
  short8 r;
  r[0] = f2s(a.x); r[1] = f2s(a.y); r[2] = f2s(a.z); r[3] = f2s(a.w);
  r[4] = f2s(b.x); r[5] = f2s(b.y); r[6] = f2s(b.z); r[7] = f2s(b.w);
  *(short8*)dst = r;
}

// fp32 -> bf16 elementwise convert; each thread handles 8 elements.
__global__ __launch_bounds__(256) void convert_f32_bf16(
    const float* __restrict__ src, bf16* __restrict__ dst, int n) {
  const int i = (blockIdx.x * 256 + threadIdx.x) * 8;
  if (i + 7 < n) cvt8(src + i, dst + i);
}

// ---------------------------------------------------------------------------
// Fused one-launch preprocessing (full-batch path): x + 4 weight converts +
// table precompute in a single dispatch (was 6 launches; saves 5 dispatch
// boundaries and overlaps the small weight converts under the big x convert).
// blocks [0,8192): x (16.7M elems); [8192,8704): wq; ... ; [10240]: tables.
// ---------------------------------------------------------------------------
__global__ __launch_bounds__(256) void convert_all(
    const float* __restrict__ x,  bf16* __restrict__ xb,
    const float* __restrict__ wq, bf16* __restrict__ wqb,
    const float* __restrict__ wk, bf16* __restrict__ wkb,
    const float* __restrict__ wv, bf16* __restrict__ wvb,
    const float* __restrict__ wo, bf16* __restrict__ wob,
    const float* __restrict__ eqh, const float* __restrict__ eqw,
    const float* __restrict__ ekh, const float* __restrict__ ekw,
    const float* __restrict__ evh, const float* __restrict__ evw,
    bf16* __restrict__ ews, float* __restrict__ S4f)
{
  const int b = blockIdx.x;
  const int t = threadIdx.x;
  if (b < 8192) {
    const int i = (b * 256 + t) * 8;
    cvt8(x + i, xb + i);
    return;
  }
  if (b < 10240) {
    const int wsel = (b - 8192) >> 9;           // 0..3
    const int i = (((b - 8192) & 511) * 256 + t) * 8;
    const float* s = (wsel == 0) ? wq : (wsel == 1) ? wk : (wsel == 2) ? wv : wo;
    bf16* d = (wsel == 0) ? wqb : (wsel == 1) ? wkb : (wsel == 2) ? wvb : wob;
    cvt8(s + i, d + i);
    return;
  }
  // ---- tables (one block) ----
  if (t < 96) {
    const int tb = t >> 4, row = t & 15;
    const float* src[6] = {eqh, eqw, ekh, ekw, evh, evw};
    bf16* dst = ews + tb * 1024 + row * 64;
    if (row < 15) {
      const float* s = src[tb] + row * 64;
      #pragma unroll
      for (int d = 0; d < 64; d += 8) cvt8(s + d, dst + d);
    } else {
      const short8 z = {0, 0, 0, 0, 0, 0, 0, 0};
      #pragma unroll
      for (int d = 0; d < 64; d += 8) *(short8*)(dst + d) = z;
    }
  }
  if (t < 225) {
    const int r = t / 15, c = t % 15;
    float s = 0.f;
    for (int d = 0; d < 64; ++d)
      s += (eqh[r * 64 + d] + eqw[c * 64 + d]) * (ekh[r * 64 + d] + ekw[c * 64 + d]);
    S4f[t] = s;
  }
}

// One-block precompute (halved path only).
__global__ __launch_bounds__(256) void precompute_tables(
    const float* __restrict__ eqh, const float* __restrict__ eqw,
    const float* __restrict__ ekh, const float* __restrict__ ekw,
    const float* __restrict__ evh, const float* __restrict__ evw,
    bf16* __restrict__ ews, float* __restrict__ S4f)
{
  const int t = threadIdx.x;
  if (t < 96) {
    const int tb = t >> 4, row = t & 15;
    const float* src[6] = {eqh, eqw, ekh, ekw, evh, evw};
    bf16* dst = ews + tb * 1024 + row * 64;
    if (row < 15) {
      const float* s = src[tb] + row * 64;
      #pragma unroll
      for (int d = 0; d < 64; d += 8) cvt8(s + d, dst + d);
    } else {
      const short8 z = {0, 0, 0, 0, 0, 0, 0, 0};
      #pragma unroll
      for (int d = 0; d < 64; d += 8) *(short8*)(dst + d) = z;
    }
  }
  if (t < 225) {
    const int r = t / 15, c = t % 15;
    float s = 0.f;
    for (int d = 0; d < 64; ++d)
      s += (eqh[r * 64 + d] + eqw[c * 64 + d]) * (ekh[r * 64 + d] + ekw[c * 64 + d]);
    S4f[t] = s;
  }
}

// ---------------------------------------------------------------------------
// 256x256-tile GEMM, C = A @ W^T (+bias), bf16 inputs.
// 8 waves (2M x 4N), 128x64 per wave. BK=32, 4-deep LDS ring (4 x 32KB),
// prefetch depth 3 K-tiles, counted vmcnt(8), ONE barrier per tile (r6 —
// equal-best with r3; plateau at ~134us/33% MfmaUtil across all schedule
// variants r3-r6 -> structure frozen).
//
// T1: XCD k owns bx in [k*nx/8,(k+1)*nx/8) for ALL by panels (FETCH
// 203->74MB, r2->r3).
//
// Epilogue (r7): scatter stores reordered ni-INNERMOST — each (mi,r) row's
// 64 consecutive cols (128B bf16 / 256B fp32) are dirtied by 4 back-to-back
// stores, so HBM sectors are written once. r3-r6 ni-outer order measured
// WRITE 220MB vs 96MB ideal (~2x partial-sector writeback).
// ---------------------------------------------------------------------------
template <int TAG>
__global__ __launch_bounds__(512, 2) void gemm256(
    const bf16* __restrict__ A,
    const bf16* __restrict__ W0, const bf16* __restrict__ W1, const bf16* __restrict__ W2,
    const float* __restrict__ bias, int hasBias,
    bf16* __restrict__ O0, bf16* __restrict__ O1, bf16* __restrict__ O2,
    float* __restrict__ Ofp, int outF32)
{
  __shared__ bf16 lds[65536];   // 128 KB: 4 bufs x (A 8192 + B 8192 elems)

  const int nx = gridDim.x;
  const int orig = blockIdx.y * nx + blockIdx.x;
  const int xcd = orig & 7;
  const int c = orig >> 3;
  const int bxp = nx >> 3;               // bx per XCD (nx % 8 == 0 in all paths)
  const int bx = xcd * bxp + (c % bxp);
  const int by = c / bxp;

  const int m0 = bx * 256;
  const int which = by >> 2;
  const bf16* W = (which == 0) ? W0 : (which == 1) ? W1 : W2;
  bf16* O = (which == 0) ? O0 : (which == 1) ? O1 : O2;
  const int n0 = (by & 3) * 256;

  const int t = threadIdx.x;
  const int lane = t & 63, w = t >> 6;
  const int wm = w >> 2, wn = w & 3;
  const int quad = lane >> 4, n16 = lane & 15;

  // staging source coordinates (inverse of the LDS st_16x32 swizzle)
  const int srow = (t >> 6) * 16 + ((t & 63) >> 2);
  const int scol = ((t & 3) * 8) ^ (((t >> 5) & 1) << 4);
  const bf16* Abase = A + (m0 + srow) * 1024 + scol;
  const bf16* Bbase = W + (n0 + srow) * 1024 + scol;
  const int wdst = w * 512;               // wave-uniform LDS dest (HW adds lane*16B)

  // fragment read offsets (swizzled)
  const int swzq = (quad * 8) ^ ((n16 >> 3) << 4);
  const int aoff = wm * 4096 + n16 * 32 + swzq;   // + mi*512 (+2048 for mi 4..7)
  const int boff = wn * 2048 + n16 * 32 + swzq;   // + ni*512

  floatx4 acc[8][4];
  const floatx4 zero4 = {0.f, 0.f, 0.f, 0.f};
  #pragma unroll
  for (int mi = 0; mi < 8; ++mi)
    #pragma unroll
    for (int ni = 0; ni < 4; ++ni) acc[mi][ni] = zero4;

  // prologue: stage tiles 0,1,2 into ring slots 0,1,2
  #pragma unroll
  for (int p = 0; p < 3; ++p) {
    const bf16* ga = Abase + p * 32;
    bf16* la = lds + p * 16384 + wdst;
    gl_lds16(ga, la); gl_lds16(ga + 131072, la + 4096);
    const bf16* gb = Bbase + p * 32;
    bf16* lb = lds + p * 16384 + 8192 + wdst;
    gl_lds16(gb, lb); gl_lds16(gb + 131072, lb + 4096);
  }
  VMCNT(8);      // tile 0 landed; tiles 1,2 (8 loads) stay in flight
  bar();

#define TILE_STEP(TT, DOSTAGE, WAITSEQ) do {                                   \
    const bf16* bA_ = lds + ((TT) & 3) * 16384;                                \
    const bf16* bB_ = bA_ + 8192;                                              \
    short8 af_[4], bq_[4];                                                     \
    _Pragma("unroll")                                                          \
    for (int mi = 0; mi < 4; ++mi)                                             \
      af_[mi] = *(const short8*)(bA_ + aoff + mi * 512);                       \
    _Pragma("unroll")                                                          \
    for (int ni = 0; ni < 4; ++ni)                                             \
      bq_[ni] = *(const short8*)(bB_ + boff + ni * 512);                       \
    if (DOSTAGE) {                                                             \
      const bf16* g_ = Abase + ((TT) + 3) * 32;                                \
      bf16* l_ = lds + (((TT) + 3) & 3) * 16384 + wdst;                        \
      gl_lds16(g_, l_); gl_lds16(g_ + 131072, l_ + 4096);                      \
    }                                                                          \
    __builtin_amdgcn_s_setprio(1);                                             \
    _Pragma("unroll")                                                          \
    for (int mi = 0; mi < 4; ++mi)                                             \
      _Pragma("unroll")                                                        \
      for (int ni = 0; ni < 4; ++ni)                                           \
        acc[mi][ni] = MFMA16(af_[mi], bq_[ni], acc[mi][ni]);                   \
    __builtin_amdgcn_s_setprio(0);                                             \
    _Pragma("unroll")                                                          \
    for (int mi = 0; mi < 4; ++mi)                                             \
      af_[mi] = *(const short8*)(bA_ + aoff + 2048 + mi * 512);                \
    if (DOSTAGE) {                                                             \
      const bf16* g_ = Bbase + ((TT) + 3) * 32;                                \
      bf16* l_ = lds + (((TT) + 3) & 3) * 16384 + 8192 + wdst;                 \
      gl_lds16(g_, l_); gl_lds16(g_ + 131072, l_ + 4096);                      \
    }                                                                          \
    __builtin_amdgcn_s_setprio(1);                                             \
    _Pragma("unroll")                                                          \
    for (int mi = 0; mi < 4; ++mi)                                             \
      _Pragma("unroll")                                                        \
      for (int ni = 0; ni < 4; ++ni)                                           \
        acc[mi + 4][ni] = MFMA16(af_[mi], bq_[ni], acc[mi + 4][ni]);           \
    __builtin_amdgcn_s_setprio(0);                                             \
    WAITSEQ;                                                                   \
  } while (0)

  #pragma unroll 1
  for (int tt = 0; tt < 29; ++tt) {
    TILE_STEP(tt, 1, VMCNT(8); bar());
  }
  TILE_STEP(29, 0, VMCNT(4); bar());
  TILE_STEP(30, 0, VMCNT(0); bar());
  TILE_STEP(31, 0, (void)0);
#undef TILE_STEP

  // ---- epilogue: scatter stores, ni-INNERMOST (full 128B/256B per row
  // dirtied back-to-back -> single sector writeback; r7) ----
  float bvv[4];
  #pragma unroll
  for (int ni = 0; ni < 4; ++ni)
    bvv[ni] = hasBias ? bias[n0 + wn * 64 + ni * 16 + n16] : 0.f;
  #pragma unroll
  for (int mi = 0; mi < 8; ++mi) {
    #pragma unroll
    for (int r = 0; r < 4; ++r) {
      const int row = m0 + wm * 128 + mi * 16 + quad * 4 + r;
      if (outF32) {
        #pragma unroll
        for (int ni = 0; ni < 4; ++ni)
          Ofp[row * 1024 + n0 + wn * 64 + ni * 16 + n16] = acc[mi][ni][r] + bvv[ni];
      } else {
        #pragma unroll
        for (int ni = 0; ni < 4; ++ni)
          O[row * 1024 + n0 + wn * 64 + ni * 16 + n16] =
              __float2bfloat16(acc[mi][ni][r] + bvv[ni]);
      }
    }
  }
}

// Legacy 128^2-tile GEMM — kept only for the fp32-weight fallback path.
template <int TAG>
__global__ __launch_bounds__(256) void gemm_bt(
    const bf16* __restrict__ A,
    const void* __restrict__ W0, const void* __restrict__ W1, const void* __restrict__ W2,
    int wBf,
    const float* __restrict__ bias, int hasBias,
    bf16* __restrict__ O0, bf16* __restrict__ O1, bf16* __restrict__ O2,
    float* __restrict__ Ofp, int outF32)
{
  __shared__ bf16 As[128 * 64];
  __shared__ bf16 Bs[128 * 64];

  const int m0 = blockIdx.x * 128;
  const int by = blockIdx.y;
  const int which = by >> 3;
  const void* W = (which == 0) ? W0 : (which == 1) ? W1 : W2;
  bf16* O = (which == 0) ? O0 : (which == 1) ? O1 : O2;
  const int n0 = (by & 7) * 128;

  const int t = threadIdx.x;
  const int lane = t & 63, w = t >> 6;
  const int lrow = lane >> 3, lcol = (lane & 7) * 8;
  const int wm = w >> 1, wn = w & 1;
  const int quad = lane >> 4, n16 = lane & 15;

  const int swzA = ((lrow & 1) << 5) | (((lrow >> 1) & 3) << 3);
  const int gcol = lcol ^ swzA;
  const int swzR = ((n16 & 1) << 5) | (((n16 >> 1) & 3) << 3);

  floatx4 acc[4][4];
  const floatx4 zero4 = {0.f, 0.f, 0.f, 0.f};
  #pragma unroll
  for (int mi = 0; mi < 4; ++mi)
    #pragma unroll
    for (int ni = 0; ni < 4; ++ni) acc[mi][ni] = zero4;

  const int arowb = m0 + w * 32 + lrow;
  const int browb = n0 + w * 32 + lrow;
  bf16* lau = As + w * 2048;
  bf16* lbu = Bs + w * 2048;

  if (wBf) {
    const bf16* Wb = (const bf16*)W;
    for (int k0 = 0; k0 < 1024; k0 += 64) {
      if (k0) __syncthreads();
      const bf16* ga = A + arowb * 1024 + k0 + gcol;
      const bf16* gw = Wb + browb * 1024 + k0 + gcol;
      #pragma unroll
      for (int c = 0; c < 4; ++c) {
        gl_lds16(ga + c * 8192, lau + c * 512);
        gl_lds16(gw + c * 8192, lbu + c * 512);
      }
      __syncthreads();
      #pragma unroll
      for (int ks = 0; ks < 2; ++ks) {
        short8 af[4], bfv[4];
        #pragma unroll
        for (int mi = 0; mi < 4; ++mi)
          af[mi] = *(const short8*)(As + (wm * 64 + mi * 16 + n16) * 64 +
                                    ((ks * 32 + quad * 8) ^ swzR));
        #pragma unroll
        for (int ni = 0; ni < 4; ++ni)
          bfv[ni] = *(const short8*)(Bs + (wn * 64 + ni * 16 + n16) * 64 +
                                     ((ks * 32 + quad * 8) ^ swzR));
        #pragma unroll
        for (int mi = 0; mi < 4; ++mi)
          #pragma unroll
          for (int ni = 0; ni < 4; ++ni)
            acc[mi][ni] = MFMA16(af[mi], bfv[ni], acc[mi][ni]);
      }
    }
  } else {
    const float* Wf = (const float*)W;
    for (int k0 = 0; k0 < 1024; k0 += 64) {
      short8 rb[4];
      #pragma unroll
      for (int c = 0; c < 4; ++c) {
        const float* f = Wf + (browb + c * 8) * 1024 + k0 + gcol;
        float4 a = *(const float4*)f;
        float4 b = *(const float4*)(f + 4);
        short8 r;
        r[0] = f2s(a.x); r[1] = f2s(a.y); r[2] = f2s(a.z); r[3] = f2s(a.w);
        r[4] = f2s(b.x); r[5] = f2s(b.y); r[6] = f2s(b.z); r[7] = f2s(b.w);
        rb[c] = r;
      }
      if (k0) __syncthreads();
      const bf16* ga = A + arowb * 1024 + k0 + gcol;
      #pragma unroll
      for (int c = 0; c < 4; ++c) {
        gl_lds16(ga + c * 8192, lau + c * 512);
        *(short8*)(lbu + lane * 8 + c * 512) = rb[c];
      }
      __syncthreads();
      #pragma unroll
      for (int ks = 0; ks < 2; ++ks) {
        short8 af[4], bfv[4];
        #pragma unroll
        for (int mi = 0; mi < 4; ++mi)
          af[mi] = *(const short8*)(As + (wm * 64 + mi * 16 + n16) * 64 +
                                    ((ks * 32 + quad * 8) ^ swzR));
        #pragma unroll
        for (int ni = 0; ni < 4; ++ni)
          bfv[ni] = *(const short8*)(Bs + (wn * 64 + ni * 16 + n16) * 64 +
                                     ((ks * 32 + quad * 8) ^ swzR));
        #pragma unroll
        for (int mi = 0; mi < 4; ++mi)
          #pragma unroll
          for (int ni = 0; ni < 4; ++ni)
            acc[mi][ni] = MFMA16(af[mi], bfv[ni], acc[mi][ni]);
      }
    }
  }

  #pragma unroll
  for (int ni = 0; ni < 4; ++ni) {
    const int col = n0 + wn * 64 + ni * 16 + n16;
    const float bv = hasBias ? bias[col] : 0.f;
    #pragma unroll
    for (int mi = 0; mi < 4; ++mi) {
      #pragma unroll
      for (int r = 0; r < 4; ++r) {
        const int row = m0 + wm * 64 + mi * 16 + quad * 4 + r;
        if (outF32) Ofp[row * 1024 + col] = acc[mi][ni][r] + bv;
        else        O[row * 1024 + col] = __float2bfloat16(acc[mi][ni][r] + bv);
      }
    }
  }
}

// One block per (b_local, h). Rel tables via MFMA; binning in registers.
__global__ __launch_bounds__(256, 3) void attn_rel(
    const bf16* __restrict__ Q, const bf16* __restrict__ Km, const bf16* __restrict__ V,
    const bf16* __restrict__ ews, const float* __restrict__ S4f,
    bf16* __restrict__ Ctx)
{
  __shared__ bf16 vT[64][106];      // [d][k]: k<64 v[j=k][d]; 64..78 ev_h; 79..93 ev_w; 94,95 zero
  __shared__ bf16 pa[64][104];      // [i][k]: k<64 attn; 64..78 P_h; 79..93 P_w; 94,95 zero
  __shared__ float Ahs[64][16], Aws[64][16];   // q_i . ek_h[r] / ek_w[c]  (col 15 = 0)
  __shared__ float Bhs[15][64], Bws[15][64];   // eq_h[r] . k_j / eq_w[c] . k_j
  __shared__ float S4s[225];

  const int t = threadIdx.x;
  const int b = blockIdx.x >> 4, h = blockIdx.x & 15;
  const int base = b * 65536 + h * 64;
  const int lane = t & 63, w = t >> 6;
  const int quad = lane >> 4, n16 = lane & 15;

  // ---- phase 0: fragment loads straight from global ----
  const bf16* qrow = Q + base + (w * 16 + n16) * 1024 + quad * 8;
  short8 aq0 = *(const short8*)(qrow);
  short8 aq1 = *(const short8*)(qrow + 32);
  short8 bk0[4], bk1[4];
  #pragma unroll
  for (int nj = 0; nj < 4; ++nj) {
    const bf16* krow = Km + base + (nj * 16 + n16) * 1024 + quad * 8;
    bk0[nj] = *(const short8*)(krow);
    bk1[nj] = *(const short8*)(krow + 32);
  }
  short8 ebf[4][2];   // B-frags of eqh,eqw,ekh,ekw (row 15 zeroed by precompute)
  #pragma unroll
  for (int tb = 0; tb < 4; ++tb) {
    const bf16* er = ews + tb * 1024 + n16 * 64 + quad * 8;
    ebf[tb][0] = *(const short8*)(er);
    ebf[tb][1] = *(const short8*)(er + 32);
  }

  // ---- phase 1: stage transposed V + ev augmentation + S4; zero pads ----
  {
    const int r = t >> 2, c0 = (t & 3) * 16;
    const bf16* vrow = V + base + r * 1024 + c0;
    int4 v0 = *(const int4*)(vrow);
    int4 v1 = *(const int4*)(vrow + 8);
    const unsigned short* p0 = (const unsigned short*)&v0;
    const unsigned short* p1 = (const unsigned short*)&v1;
    #pragma unroll
    for (int ii = 0; ii < 8; ++ii) {
      *(unsigned short*)&vT[c0 + ii][r] = p0[ii];
      *(unsigned short*)&vT[c0 + 8 + ii][r] = p1[ii];
    }
    if (t < 60) {
      const int r2 = t >> 2, d0 = (t & 3) * 16;
      ushort8 pe0 = *(const ushort8*)(ews + 4096 + r2 * 64 + d0);
      ushort8 pe1 = *(const ushort8*)(ews + 4096 + r2 * 64 + d0 + 8);
      ushort8 pf0 = *(const ushort8*)(ews + 5120 + r2 * 64 + d0);
      ushort8 pf1 = *(const ushort8*)(ews + 5120 + r2 * 64 + d0 + 8);
      #pragma unroll
      for (int ii = 0; ii < 8; ++ii) {
        *(unsigned short*)&vT[d0 + ii][64 + r2] = pe0[ii];
        *(unsigned short*)&vT[d0 + 8 + ii][64 + r2] = pe1[ii];
        *(unsigned short*)&vT[d0 + ii][79 + r2] = pf0[ii];
        *(unsigned short*)&vT[d0 + 8 + ii][79 + r2] = pf1[ii];
      }
    }
    if (t < 64) {
      *(unsigned short*)&vT[t][94] = 0; *(unsigned short*)&vT[t][95] = 0;
      *(unsigned short*)&pa[t][94] = 0; *(unsigned short*)&pa[t][95] = 0;
    }
    if (t < 225) S4s[t] = S4f[t];
  }

  // ---- phase A: MFMAs — QK^T + rel tables; write tables to LDS ----
  floatx4 cqk[4];
  #pragma unroll
  for (int nj = 0; nj < 4; ++nj) {
    floatx4 c = {0.f, 0.f, 0.f, 0.f};
    c = MFMA16(aq0, bk0[nj], c);
    c = MFMA16(aq1, bk1[nj], c);
    cqk[nj] = c;
  }
  {
    floatx4 cah = {0.f, 0.f, 0.f, 0.f}, caw = cah, cbh = cah, cbw = cah;
    cah = MFMA16(aq0, ebf[2][0], cah); cah = MFMA16(aq1, ebf[2][1], cah);
    caw = MFMA16(aq0, ebf[3][0], caw); caw = MFMA16(aq1, ebf[3][1], caw);
    cbh = MFMA16(bk0[w], ebf[0][0], cbh); cbh = MFMA16(bk1[w], ebf[0][1], cbh);
    cbw = MFMA16(bk0[w], ebf[1][0], cbw); cbw = MFMA16(bk1[w], ebf[1][1], cbw);
    #pragma unroll
    for (int r = 0; r < 4; ++r) {
      const int i = w * 16 + quad * 4 + r;   // row i for Ah/Aw; key index j for Bh/Bw
      Ahs[i][n16] = cah[r];
      Aws[i][n16] = caw[r];
      if (n16 < 15) { Bhs[n16][i] = cbh[r]; Bws[n16][i] = cbw[r]; }
    }
  }
  __syncthreads();

  // ---- phase 3: rel add + softmax + register binning; write pa (wave-own rows) ----
  const int i_base = w * 16 + quad * 4;
  float xv[4][4];
  #pragma unroll
  for (int nj = 0; nj < 4; ++nj) {
    const int j = nj * 16 + n16;
    const int rowj = j >> 3, colj = j & 7;
    #pragma unroll
    for (int r = 0; r < 4; ++r) {
      const int i = i_base + r;
      const int rowi = i >> 3, coli = i & 7;
      const int rr = rowi - rowj + 7, rc = coli - colj + 7;
      xv[r][nj] = (cqk[nj][r] + Ahs[i][rr] + Aws[i][rc] + Bhs[rr][j] + Bws[rc][j]
                   + S4s[rr * 15 + rc]) * 0.125f;
    }
  }
  #pragma unroll
  for (int r = 0; r < 4; ++r) {
    const int i = i_base + r;
    const int rowi = i >> 3, coli = i & 7;
    float mx = fmaxf(fmaxf(xv[r][0], xv[r][1]), fmaxf(xv[r][2], xv[r][3]));
    #pragma unroll
    for (int off = 1; off < 16; off <<= 1) mx = fmaxf(mx, __shfl_xor(mx, off));
    float p[4];
    float sm = 0.f;
    #pragma unroll
    for (int nj = 0; nj < 4; ++nj) { p[nj] = __expf(xv[r][nj] - mx); sm += p[nj]; }
    #pragma unroll
    for (int off = 1; off < 16; off <<= 1) sm += __shfl_xor(sm, off);
    const float inv = 1.0f / sm;
    #pragma unroll
    for (int nj = 0; nj < 4; ++nj) {
      p[nj] *= inv;
      pa[i][nj * 16 + n16] = __float2bfloat16(p[nj]);
    }
    // P_h: butterfly over the 8 lanes sharing n16>>3 -> Ph'[i][g = nj*2 + (n16>>3)]
    float ph[4];
    #pragma unroll
    for (int nj = 0; nj < 4; ++nj) {
      float v = p[nj];
      v += __shfl_xor(v, 1); v += __shfl_xor(v, 2); v += __shfl_xor(v, 4);
      ph[nj] = v;
    }
    // P_w: Pw'[i][c = n16&7]
    float s4 = p[0] + p[1] + p[2] + p[3];
    float pw = s4 + __shfl_xor(s4, 8);
    if ((n16 & 7) == 0) {
      const int hh = n16 >> 3;
      #pragma unroll
      for (int nj = 0; nj < 4; ++nj) {
        const int g = nj * 2 + hh;
        pa[i][64 + rowi + 7 - g] = __float2bfloat16(ph[nj]);
      }
    } else if (n16 < 8) {
      const int z = n16 - 1;
      pa[i][64 + (z < rowi ? z : z + 8)] = __float2bfloat16(0.f);
    }
    if (n16 < 8) {
      pa[i][79 + coli + 7 - n16] = __float2bfloat16(pw);
    } else {
      const int z = n16 - 8;
      pa[i][79 + (z < coli ? z : z + 8)] = __float2bfloat16(0.f);  // z=7 hits zero-pad col 94
    }
  }
  __threadfence_block();   // pa writes -> same-wave pa reads below

  // ---- phase 5: ctx = attn_aug (64x96) @ Vaug (96x64) ----
  short8 ap[3];
  #pragma unroll
  for (int ksb = 0; ksb < 3; ++ksb)
    ap[ksb] = *(const short8*)&pa[w * 16 + n16][ksb * 32 + quad * 8];
  #pragma unroll
  for (int nj = 0; nj < 4; ++nj) {
    floatx4 c = {0.f, 0.f, 0.f, 0.f};
    #pragma unroll
    for (int ksb = 0; ksb < 3; ++ksb) {
      short8 bv = *(const short8*)&vT[nj * 16 + n16][ksb * 32 + quad * 8];
      c = MFMA16(ap[ksb], bv, c);
    }
    #pragma unroll
    for (int r = 0; r < 4; ++r) {
      const int i = i_base + r;
      Ctx[base + i * 1024 + nj * 16 + n16] = __float2bfloat16(c[r]);
    }
  }
}

extern "C" void kernel_launch(void* const* d_in, const int* in_sizes, int n_in,
                              void* d_out, int out_size, void* d_ws, size_t ws_size,
                              hipStream_t stream) {
  const float* x   = (const float*)d_in[0];
  const float* wq  = (const float*)d_in[1];
  const float* wk  = (const float*)d_in[2];
  const float* wv  = (const float*)d_in[3];
  const float* wo  = (const float*)d_in[4];
  const float* bo  = (const float*)d_in[5];
  const float* eqh = (const float*)d_in[6];
  const float* eqw = (const float*)d_in[7];
  const float* ekh = (const float*)d_in[8];
  const float* ekw = (const float*)d_in[9];
  const float* evh = (const float*)d_in[10];
  const float* evw = (const float*)d_in[11];
  float* outf = (float*)d_out;

  // 16KB table header at the tail of ws (clear of qb/kb/weights in all modes).
  const size_t hdr = (ws_size - 16384) & ~(size_t)1023;
  bf16* ewsB = (bf16*)((char*)d_ws + hdr);
  float* S4f = (float*)((char*)d_ws + hdr + 12288);

  if (ws_size >= (size_t)73 * 1024 * 1024) {
    // -------- full-batch path: ws = q(32M) | k(32M) | weights(8M) --------
    bf16* qb = (bf16*)d_ws;
    bf16* kb = qb + 16777216;
    bf16* wqb = kb + 16777216;
    bf16* wkb = wqb + 1048576;
    bf16* wvb = wkb + 1048576;
    bf16* wob = wvb + 1048576;
    bf16* xb = (bf16*)d_out;                      // d_out[0,32M): x bf16 (dead after QKV gemm)
    bf16* vb = (bf16*)((char*)d_out + 33554432);  // d_out[32M,64M): v (dead after attn)

    convert_all<<<10241, 256, 0, stream>>>(
        x, xb, wq, wqb, wk, wkb, wv, wvb, wo, wob,
        eqh, eqw, ekh, ekw, evh, evw, ewsB, S4f);

    gemm256<0><<<dim3(64, 12), 512, 0, stream>>>(
        xb, wqb, wkb, wvb, nullptr, 0, qb, kb, vb, nullptr, 0);
    attn_rel<<<dim3(4096), 256, 0, stream>>>(qb, kb, vb, ewsB, S4f, qb);
    gemm256<1><<<dim3(64, 4), 512, 0, stream>>>(
        qb, wob, nullptr, nullptr, bo, 1, nullptr, nullptr, nullptr, outf, 1);
  } else {
    // -------- halved path --------
    precompute_tables<<<1, 256, 0, stream>>>(eqh, eqw, ekh, ekw, evh, evw, ewsB, S4f);
    bf16* xb0 = (bf16*)((char*)d_out + 16777216);   // Q1
    bf16* xb1 = (bf16*)((char*)d_out + 50331648);   // Q3
    bf16* vQ2 = (bf16*)((char*)d_out + 33554432);   // Q2
    bf16* qb = (bf16*)d_ws;
    bf16* kb = qb + 8388608;
    const int fastW = (ws_size >= (size_t)42 * 1024 * 1024) ? 1 : 0;
    bf16* wqb = kb + 8388608;
    bf16* wkb = wqb + 1048576;
    bf16* wvb = wkb + 1048576;
    bf16* wob = wvb + 1048576;

    convert_f32_bf16<<<4096, 256, 0, stream>>>(x, xb0, 8388608);
    convert_f32_bf16<<<4096, 256, 0, stream>>>(x + 8388608, xb1, 8388608);
    if (fastW) {
      convert_f32_bf16<<<512, 256, 0, stream>>>(wq, wqb, 1048576);
      convert_f32_bf16<<<512, 256, 0, stream>>>(wk, wkb, 1048576);
      convert_f32_bf16<<<512, 256, 0, stream>>>(wv, wvb, 1048576);
      convert_f32_bf16<<<512, 256, 0, stream>>>(wo, wob, 1048576);
    }

    for (int hh = 0; hh < 2; ++hh) {
      const bf16* xh = hh ? xb1 : xb0;
      if (fastW) {
        gemm256<0><<<dim3(32, 12), 512, 0, stream>>>(
            xh, wqb, wkb, wvb, nullptr, 0, qb, kb, vQ2, nullptr, 0);
      } else {
        gemm_bt<0><<<dim3(64, 24), 256, 0, stream>>>(
            xh, (const void*)wq, (const void*)wk, (const void*)wv,
            0, nullptr, 0, qb, kb, vQ2, nullptr, 0);
      }
      attn_rel<<<dim3(2048), 256, 0, stream>>>(qb, kb, vQ2, ewsB, S4f, qb);
      if (fastW) {
        gemm256<1><<<dim3(32, 4), 512, 0, stream>>>(
            qb, wob, nullptr, nullptr, bo, 1, nullptr, nullptr, nullptr,
            outf + (size_t)hh * 8388608, 1);
      } else {
        gemm_bt<1><<<dim3(64, 8), 256, 0, stream>>>(
            qb, (const void*)wo, nullptr, nullptr,
            0, bo, 1, nullptr, nullptr, nullptr,
            outf + (size_t)hh * 8388608, 1);
      }
    }
  }
}